// Round 5
// baseline (723.531 us; speedup 1.0000x reference)
//
#include <hip/hip_runtime.h>

#define HID 64

__device__ __forceinline__ float bf2f(unsigned short u) {
    return __uint_as_float(((unsigned)u) << 16);
}
__device__ __forceinline__ unsigned short f2bf(float f) {
    unsigned u = __float_as_uint(f);
    u += 0x7FFF + ((u >> 16) & 1);  // RNE
    return (unsigned short)(u >> 16);
}

// ================= CSR build =================
__global__ void zero2(int* counts, int* cursor, int n) {
    int i = blockIdx.x * blockDim.x + threadIdx.x;
    if (i < n) { counts[i] = 0; cursor[i] = 0; }
}

__global__ void hist_dst(const int* __restrict__ dst, int* counts, int E) {
    int e = blockIdx.x * blockDim.x + threadIdx.x;
    if (e < E) atomicAdd(&counts[dst[e]], 1);
}

// per-block inclusive scan of counts -> tmp; block totals -> bsum; also dinv
__global__ void scan1(const int* __restrict__ counts, int* __restrict__ tmp,
                      int* __restrict__ bsum, float* __restrict__ dinv, int n) {
    __shared__ int s[256];
    int t = threadIdx.x;
    int i = blockIdx.x * 256 + t;
    int v = (i < n) ? counts[i] : 0;
    if (i < n) dinv[i] = rsqrtf((float)v + 1.0f);  // deg incl. self-loop
    s[t] = v;
    __syncthreads();
#pragma unroll
    for (int d = 1; d < 256; d <<= 1) {
        int x = (t >= d) ? s[t - d] : 0;
        __syncthreads();
        s[t] += x;
        __syncthreads();
    }
    if (i < n) tmp[i] = s[t];
    if (t == 255) bsum[blockIdx.x] = s[255];
}

// exclusive scan of block sums (NB <= 256)
__global__ void scan2(const int* __restrict__ bsum, int* __restrict__ boff, int nb) {
    __shared__ int s[256];
    int t = threadIdx.x;
    s[t] = (t < nb) ? bsum[t] : 0;
    __syncthreads();
#pragma unroll
    for (int d = 1; d < 256; d <<= 1) {
        int x = (t >= d) ? s[t - d] : 0;
        __syncthreads();
        s[t] += x;
        __syncthreads();
    }
    if (t < nb) boff[t] = s[t] - bsum[t];  // exclusive
}

__global__ void scan3b(const int* __restrict__ counts, const int* __restrict__ tmp,
                       const int* __restrict__ boff, int* __restrict__ rowptr, int n, int E) {
    int b = blockIdx.x;
    int i = b * 256 + threadIdx.x;
    if (i < n) rowptr[i] = tmp[i] - counts[i] + boff[b];
    if (i == n - 1) rowptr[n] = tmp[i] + boff[b];  // == E
}

// bucket-fill CSR: col = src only (coef folded into hws)
__global__ void csr_fill(const int* __restrict__ eidx, const int* __restrict__ rowptr,
                         int* __restrict__ cursor, int* __restrict__ col, int E) {
    int e = blockIdx.x * blockDim.x + threadIdx.x;
    if (e >= E) return;
    int s = eidx[e];
    int d = eidx[E + e];
    int pos = rowptr[d] + atomicAdd(&cursor[d], 1);
    col[pos] = s;
}

// ================= dense ops =================
__global__ void input_proj(const float* __restrict__ x, const float* __restrict__ Win,
                           const float* __restrict__ bin, float* __restrict__ h, int n) {
    int t = blockIdx.x * blockDim.x + threadIdx.x;
    int v = t >> 6, j = t & 63;
    if (v >= n) return;
    float acc = bin[j];
#pragma unroll
    for (int k = 0; k < 4; ++k) acc += x[v * 4 + k] * Win[k * 64 + j];
    h[t] = acc;
}

// hws = (h @ W) * dinv stored bf16.  16 nodes/block, 4 nodes/wave:
// one wl LDS read per k shared across 4 accumulators (LDS-issue bound kernel;
// reads/output 128 -> 80, W staging amortized 4x). Only 4 accs: no spill.
__global__ void gemm_hws(const float* __restrict__ h, const float* __restrict__ W,
                         const float* __restrict__ dinv, unsigned short* __restrict__ hws,
                         int n) {
    __shared__ float wl[64 * 64];
    __shared__ float hl[16 * 64];
    int tid = threadIdx.x;
#pragma unroll
    for (int i = 0; i < 16; ++i) wl[tid + 256 * i] = W[tid + 256 * i];
    int vbase = blockIdx.x * 16;
#pragma unroll
    for (int i = 0; i < 4; ++i) {
        int idx = tid + 256 * i;           // 0..1023 ; node = idx>>6, feat = idx&63
        int vv = vbase + (idx >> 6);
        hl[idx] = (vv < n) ? h[(size_t)vv * 64 + (idx & 63)] : 0.f;
    }
    __syncthreads();
    int j = tid & 63;
    int w = tid >> 6;                      // wave id: nodes vbase + w*4 .. +3
    const float* hr = &hl[(w * 4) * 64];
    float a0 = 0.f, a1 = 0.f, a2 = 0.f, a3 = 0.f;
#pragma unroll
    for (int k = 0; k < 64; ++k) {
        float wv = wl[k * 64 + j];         // per-lane, 2-way alias (free)
        a0 += hr[k] * wv;                  // wave-uniform LDS broadcasts
        a1 += hr[64 + k] * wv;
        a2 += hr[128 + k] * wv;
        a3 += hr[192 + k] * wv;
    }
    int v0 = vbase + w * 4;
    if (v0 + 0 < n) hws[(size_t)(v0 + 0) * 64 + j] = f2bf(a0 * dinv[v0 + 0]);
    if (v0 + 1 < n) hws[(size_t)(v0 + 1) * 64 + j] = f2bf(a1 * dinv[v0 + 1]);
    if (v0 + 2 < n) hws[(size_t)(v0 + 2) * 64 + j] = f2bf(a2 * dinv[v0 + 2]);
    if (v0 + 3 < n) hws[(size_t)(v0 + 3) * 64 + j] = f2bf(a3 * dinv[v0 + 3]);
}

// pull aggregate (bf16) + bias + BN(eval) + ReLU + residual.
// Wave = 4 groups x 16 lanes; group handles one node; lane holds 4 feats
// (ushort4): one load instruction fetches 4 edges x 128B = 512B, 4 independent
// edge streams per wave for MLP. h residual read/write is float4.
__global__ void gather_finalize(const int* __restrict__ rowptr, const int* __restrict__ col,
                                const unsigned short* __restrict__ hws,
                                const float* __restrict__ dinv, float* __restrict__ h,
                                const float* __restrict__ cb, const float* __restrict__ gamma,
                                const float* __restrict__ beta, const float* __restrict__ mean,
                                const float* __restrict__ var, int n) {
    int tid = threadIdx.x;
    int lane = tid & 63, wave = tid >> 6;
    int grp = lane >> 4, gl = lane & 15;
    int v = blockIdx.x * 16 + wave * 4 + grp;
    bool valid = v < n;
    int vv = valid ? v : 0;
    int j0 = gl * 4;
    const ushort4* hws4 = (const ushort4*)hws;
    size_t rowq = (size_t)vv * 16 + gl;       // index into ushort4 view
    ushort4 m = hws4[rowq];                   // self term (already * dinv[v])
    float s0 = bf2f(m.x), s1 = bf2f(m.y), s2 = bf2f(m.z), s3 = bf2f(m.w);
    int beg = rowptr[vv];
    int end = valid ? rowptr[vv + 1] : beg;
    int e = beg;
    for (; e + 3 < end; e += 4) {
        int c0 = col[e], c1 = col[e + 1], c2 = col[e + 2], c3 = col[e + 3];
        ushort4 m0 = hws4[(size_t)c0 * 16 + gl];
        ushort4 m1 = hws4[(size_t)c1 * 16 + gl];
        ushort4 m2 = hws4[(size_t)c2 * 16 + gl];
        ushort4 m3 = hws4[(size_t)c3 * 16 + gl];
        s0 += bf2f(m0.x) + bf2f(m1.x) + bf2f(m2.x) + bf2f(m3.x);
        s1 += bf2f(m0.y) + bf2f(m1.y) + bf2f(m2.y) + bf2f(m3.y);
        s2 += bf2f(m0.z) + bf2f(m1.z) + bf2f(m2.z) + bf2f(m3.z);
        s3 += bf2f(m0.w) + bf2f(m1.w) + bf2f(m2.w) + bf2f(m3.w);
    }
    for (; e < end; ++e) {
        ushort4 me = hws4[(size_t)col[e] * 16 + gl];
        s0 += bf2f(me.x); s1 += bf2f(me.y); s2 += bf2f(me.z); s3 += bf2f(me.w);
    }
    float di = dinv[vv];
    float4 cbv = *(const float4*)&cb[j0];
    float4 mnv = *(const float4*)&mean[j0];
    float4 vrv = *(const float4*)&var[j0];
    float4 gmv = *(const float4*)&gamma[j0];
    float4 btv = *(const float4*)&beta[j0];
    float4 hres = *(const float4*)&h[(size_t)vv * 64 + j0];
    float4 o;
    o.x = fmaxf((s0 * di + cbv.x - mnv.x) * rsqrtf(vrv.x + 1e-5f) * gmv.x + btv.x, 0.f) + hres.x;
    o.y = fmaxf((s1 * di + cbv.y - mnv.y) * rsqrtf(vrv.y + 1e-5f) * gmv.y + btv.y, 0.f) + hres.y;
    o.z = fmaxf((s2 * di + cbv.z - mnv.z) * rsqrtf(vrv.z + 1e-5f) * gmv.z + btv.z, 0.f) + hres.z;
    o.w = fmaxf((s3 * di + cbv.w - mnv.w) * rsqrtf(vrv.w + 1e-5f) * gmv.w + btv.w, 0.f) + hres.w;
    if (valid) *(float4*)&h[(size_t)vv * 64 + j0] = o;
}

// out = x + relu(h@W1+b1) @ W2 + b2 ; one wave per node (proven, unchanged)
__global__ void mlp_out(const float* __restrict__ h, const float* __restrict__ x,
                        const float* __restrict__ W1, const float* __restrict__ b1,
                        const float* __restrict__ W2, const float* __restrict__ b2,
                        float* __restrict__ out, int n) {
    __shared__ float wl[64 * 64];
    __shared__ float hl[256];
    int tid = threadIdx.x;
#pragma unroll
    for (int i = 0; i < 16; ++i) wl[tid + 256 * i] = W1[tid + 256 * i];
    int v = blockIdx.x * 4 + (tid >> 6);
    int j = tid & 63;
    bool valid = v < n;
    hl[tid] = valid ? h[(size_t)v * 64 + j] : 0.f;
    __syncthreads();
    float acc = b1[j];
    const float* hr = &hl[(tid >> 6) << 6];
#pragma unroll
    for (int k = 0; k < 64; ++k) acc += hr[k] * wl[k * 64 + j];
    float tj = fmaxf(acc, 0.f);
    float p0 = tj * W2[j * 4 + 0];
    float p1 = tj * W2[j * 4 + 1];
    float p2 = tj * W2[j * 4 + 2];
    float p3 = tj * W2[j * 4 + 3];
#pragma unroll
    for (int m = 32; m >= 1; m >>= 1) {
        p0 += __shfl_xor(p0, m, 64);
        p1 += __shfl_xor(p1, m, 64);
        p2 += __shfl_xor(p2, m, 64);
        p3 += __shfl_xor(p3, m, 64);
    }
    if (valid && j < 4) {
        float p = (j == 0) ? p0 : (j == 1) ? p1 : (j == 2) ? p2 : p3;
        out[v * 4 + j] = x[v * 4 + j] + p + b2[j];
    }
}

extern "C" void kernel_launch(void* const* d_in, const int* in_sizes, int n_in,
                              void* d_out, int out_size, void* d_ws, size_t ws_size,
                              hipStream_t stream) {
    const float* x     = (const float*)d_in[0];
    const int*   eidx  = (const int*)  d_in[1];
    const float* Win   = (const float*)d_in[2];
    const float* bin   = (const float*)d_in[3];
    const float* convw = (const float*)d_in[4];
    const float* convb = (const float*)d_in[5];
    const float* gamma = (const float*)d_in[6];
    const float* beta  = (const float*)d_in[7];
    const float* mean  = (const float*)d_in[8];
    const float* var   = (const float*)d_in[9];
    const float* W1    = (const float*)d_in[10];
    const float* b1    = (const float*)d_in[11];
    const float* W2    = (const float*)d_in[12];
    const float* b2    = (const float*)d_in[13];
    float* out = (float*)d_out;

    int n = in_sizes[0] / 4;   // 50000
    int E = in_sizes[1] / 2;   // 800000
    const int B = 256;
    int NB = (n + B - 1) / B;  // 196 blocks for the scan

    // workspace layout:
    // dinv[n] f32 | h[n*64] f32 | hws[n*64] bf16 | counts[n] | cursor[n] |
    // tmp[n] | rowptr[n+1] | bsum[256] | boff[256] | col[E]
    char* p = (char*)d_ws;
    size_t nh = (size_t)n * 64;
    float*          dinv   = (float*)p;          p += ((size_t)n + 16) * 4;
    float*          h      = (float*)p;          p += nh * 4;
    unsigned short* hws    = (unsigned short*)p; p += nh * 2;
    int*            counts = (int*)p;            p += (size_t)n * 4;
    int*            cursor = (int*)p;            p += (size_t)n * 4;
    int*            tmp    = (int*)p;            p += (size_t)n * 4;
    int*            rowptr = (int*)p;            p += ((size_t)n + 16) * 4;
    int*            bsum   = (int*)p;            p += 256 * 4;
    int*            boff   = (int*)p;            p += 256 * 4;
    int*            col    = (int*)p;            p += (size_t)E * 4;

    // ---- CSR build ----
    zero2<<<NB, B, 0, stream>>>(counts, cursor, n);
    hist_dst<<<(E + B - 1) / B, B, 0, stream>>>(eidx + E, counts, E);
    scan1<<<NB, B, 0, stream>>>(counts, tmp, bsum, dinv, n);
    scan2<<<1, B, 0, stream>>>(bsum, boff, NB);
    scan3b<<<NB, B, 0, stream>>>(counts, tmp, boff, rowptr, n, E);
    csr_fill<<<(E + B - 1) / B, B, 0, stream>>>(eidx, rowptr, cursor, col, E);

    // ---- network ----
    input_proj<<<(int)((nh + B - 1) / B), B, 0, stream>>>(x, Win, bin, h, n);
    int NB16 = (n + 15) / 16;
    for (int i = 0; i < 3; ++i) {
        gemm_hws<<<NB16, B, 0, stream>>>(h, convw + i * 4096, dinv, hws, n);
        gather_finalize<<<NB16, B, 0, stream>>>(
            rowptr, col, hws, dinv, h,
            convb + i * 64, gamma + i * 64, beta + i * 64, mean + i * 64, var + i * 64, n);
    }
    mlp_out<<<(n + 3) / 4, B, 0, stream>>>(h, x, W1, b1, W2, b2, out, n);
}

// Round 6
// 352.542 us; speedup vs baseline: 2.0523x; 2.0523x over previous
//
#include <hip/hip_runtime.h>

#define HID 64

__device__ __forceinline__ float bf2f(unsigned short u) {
    return __uint_as_float(((unsigned)u) << 16);
}
__device__ __forceinline__ unsigned short f2bf(float f) {
    unsigned u = __float_as_uint(f);
    u += 0x7FFF + ((u >> 16) & 1);  // RNE
    return (unsigned short)(u >> 16);
}

// ================= CSR build =================
__global__ void zero2(int* counts, int* cursor, int n) {
    int i = blockIdx.x * blockDim.x + threadIdx.x;
    if (i < n) { counts[i] = 0; cursor[i] = 0; }
}

__global__ void hist_dst(const int* __restrict__ dst, int* counts, int E) {
    int e = blockIdx.x * blockDim.x + threadIdx.x;
    if (e < E) atomicAdd(&counts[dst[e]], 1);
}

// per-block inclusive scan of counts -> tmp; block totals -> bsum; also dinv
__global__ void scan1(const int* __restrict__ counts, int* __restrict__ tmp,
                      int* __restrict__ bsum, float* __restrict__ dinv, int n) {
    __shared__ int s[256];
    int t = threadIdx.x;
    int i = blockIdx.x * 256 + t;
    int v = (i < n) ? counts[i] : 0;
    if (i < n) dinv[i] = rsqrtf((float)v + 1.0f);  // deg incl. self-loop
    s[t] = v;
    __syncthreads();
#pragma unroll
    for (int d = 1; d < 256; d <<= 1) {
        int x = (t >= d) ? s[t - d] : 0;
        __syncthreads();
        s[t] += x;
        __syncthreads();
    }
    if (i < n) tmp[i] = s[t];
    if (t == 255) bsum[blockIdx.x] = s[255];
}

// exclusive scan of block sums (NB <= 256)
__global__ void scan2(const int* __restrict__ bsum, int* __restrict__ boff, int nb) {
    __shared__ int s[256];
    int t = threadIdx.x;
    s[t] = (t < nb) ? bsum[t] : 0;
    __syncthreads();
#pragma unroll
    for (int d = 1; d < 256; d <<= 1) {
        int x = (t >= d) ? s[t - d] : 0;
        __syncthreads();
        s[t] += x;
        __syncthreads();
    }
    if (t < nb) boff[t] = s[t] - bsum[t];  // exclusive
}

__global__ void scan3b(const int* __restrict__ counts, const int* __restrict__ tmp,
                       const int* __restrict__ boff, int* __restrict__ rowptr, int n, int E) {
    int b = blockIdx.x;
    int i = b * 256 + threadIdx.x;
    if (i < n) rowptr[i] = tmp[i] - counts[i] + boff[b];
    if (i == n - 1) rowptr[n] = tmp[i] + boff[b];  // == E
}

// bucket-fill CSR: col = src only (coef folded into hws)
__global__ void csr_fill(const int* __restrict__ eidx, const int* __restrict__ rowptr,
                         int* __restrict__ cursor, int* __restrict__ col, int E) {
    int e = blockIdx.x * blockDim.x + threadIdx.x;
    if (e >= E) return;
    int s = eidx[e];
    int d = eidx[E + e];
    int pos = rowptr[d] + atomicAdd(&cursor[d], 1);
    col[pos] = s;
}

// ================= dense ops =================
__global__ void input_proj(const float* __restrict__ x, const float* __restrict__ Win,
                           const float* __restrict__ bin, float* __restrict__ h, int n) {
    int t = blockIdx.x * blockDim.x + threadIdx.x;
    int v = t >> 6, j = t & 63;
    if (v >= n) return;
    float acc = bin[j];
#pragma unroll
    for (int k = 0; k < 4; ++k) acc += x[v * 4 + k] * Win[k * 64 + j];
    h[t] = acc;
}

// hws = (h @ W) * dinv stored bf16.  PROVEN R2/R4 structure — DO NOT add
// accumulators or wider unrolls: both R3 (8 acc) and R5 (4 acc) spilled to
// scratch at the compiler's 64-VGPR budget (0.5-1.0 GB HBM traffic, 10-20x
// slower). Single accumulator, wave-uniform broadcast h reads.
__global__ void gemm_hws(const float* __restrict__ h, const float* __restrict__ W,
                         const float* __restrict__ dinv, unsigned short* __restrict__ hws,
                         int n) {
    __shared__ float wl[64 * 64];
    __shared__ float hl[256];
    int tid = threadIdx.x;
#pragma unroll
    for (int i = 0; i < 16; ++i) wl[tid + 256 * i] = W[tid + 256 * i];
    int v = blockIdx.x * 4 + (tid >> 6);
    int j = tid & 63;
    bool valid = v < n;
    hl[tid] = valid ? h[(size_t)v * 64 + j] : 0.f;
    __syncthreads();
    if (!valid) return;
    const float* hr = &hl[(tid >> 6) << 6];  // wave-uniform -> LDS broadcast
    float acc = 0.f;
#pragma unroll
    for (int k = 0; k < 64; ++k) acc += hr[k] * wl[k * 64 + j];  // 2-way alias: free
    hws[(size_t)v * 64 + j] = f2bf(acc * dinv[v]);
}

// pull aggregate (bf16) + bias + BN(eval) + ReLU + residual.
// Wave = 4 groups x 16 lanes; group handles one node; lane holds 4 feats
// (ushort4): one load instruction fetches 4 edges x 128B = 512B, 4 independent
// edge streams per wave for MLP. h residual read/write is float4.
__global__ void gather_finalize(const int* __restrict__ rowptr, const int* __restrict__ col,
                                const unsigned short* __restrict__ hws,
                                const float* __restrict__ dinv, float* __restrict__ h,
                                const float* __restrict__ cb, const float* __restrict__ gamma,
                                const float* __restrict__ beta, const float* __restrict__ mean,
                                const float* __restrict__ var, int n) {
    int tid = threadIdx.x;
    int lane = tid & 63, wave = tid >> 6;
    int grp = lane >> 4, gl = lane & 15;
    int v = blockIdx.x * 16 + wave * 4 + grp;
    bool valid = v < n;
    int vv = valid ? v : 0;
    int j0 = gl * 4;
    const ushort4* hws4 = (const ushort4*)hws;
    size_t rowq = (size_t)vv * 16 + gl;       // index into ushort4 view
    ushort4 m = hws4[rowq];                   // self term (already * dinv[v])
    float s0 = bf2f(m.x), s1 = bf2f(m.y), s2 = bf2f(m.z), s3 = bf2f(m.w);
    int beg = rowptr[vv];
    int end = valid ? rowptr[vv + 1] : beg;
    int e = beg;
    for (; e + 3 < end; e += 4) {
        int c0 = col[e], c1 = col[e + 1], c2 = col[e + 2], c3 = col[e + 3];
        ushort4 m0 = hws4[(size_t)c0 * 16 + gl];
        ushort4 m1 = hws4[(size_t)c1 * 16 + gl];
        ushort4 m2 = hws4[(size_t)c2 * 16 + gl];
        ushort4 m3 = hws4[(size_t)c3 * 16 + gl];
        s0 += bf2f(m0.x) + bf2f(m1.x) + bf2f(m2.x) + bf2f(m3.x);
        s1 += bf2f(m0.y) + bf2f(m1.y) + bf2f(m2.y) + bf2f(m3.y);
        s2 += bf2f(m0.z) + bf2f(m1.z) + bf2f(m2.z) + bf2f(m3.z);
        s3 += bf2f(m0.w) + bf2f(m1.w) + bf2f(m2.w) + bf2f(m3.w);
    }
    for (; e < end; ++e) {
        ushort4 me = hws4[(size_t)col[e] * 16 + gl];
        s0 += bf2f(me.x); s1 += bf2f(me.y); s2 += bf2f(me.z); s3 += bf2f(me.w);
    }
    float di = dinv[vv];
    float4 cbv = *(const float4*)&cb[j0];
    float4 mnv = *(const float4*)&mean[j0];
    float4 vrv = *(const float4*)&var[j0];
    float4 gmv = *(const float4*)&gamma[j0];
    float4 btv = *(const float4*)&beta[j0];
    float4 hres = *(const float4*)&h[(size_t)vv * 64 + j0];
    float4 o;
    o.x = fmaxf((s0 * di + cbv.x - mnv.x) * rsqrtf(vrv.x + 1e-5f) * gmv.x + btv.x, 0.f) + hres.x;
    o.y = fmaxf((s1 * di + cbv.y - mnv.y) * rsqrtf(vrv.y + 1e-5f) * gmv.y + btv.y, 0.f) + hres.y;
    o.z = fmaxf((s2 * di + cbv.z - mnv.z) * rsqrtf(vrv.z + 1e-5f) * gmv.z + btv.z, 0.f) + hres.z;
    o.w = fmaxf((s3 * di + cbv.w - mnv.w) * rsqrtf(vrv.w + 1e-5f) * gmv.w + btv.w, 0.f) + hres.w;
    if (valid) *(float4*)&h[(size_t)vv * 64 + j0] = o;
}

// out = x + relu(h@W1+b1) @ W2 + b2 ; one wave per node (proven, unchanged)
__global__ void mlp_out(const float* __restrict__ h, const float* __restrict__ x,
                        const float* __restrict__ W1, const float* __restrict__ b1,
                        const float* __restrict__ W2, const float* __restrict__ b2,
                        float* __restrict__ out, int n) {
    __shared__ float wl[64 * 64];
    __shared__ float hl[256];
    int tid = threadIdx.x;
#pragma unroll
    for (int i = 0; i < 16; ++i) wl[tid + 256 * i] = W1[tid + 256 * i];
    int v = blockIdx.x * 4 + (tid >> 6);
    int j = tid & 63;
    bool valid = v < n;
    hl[tid] = valid ? h[(size_t)v * 64 + j] : 0.f;
    __syncthreads();
    float acc = b1[j];
    const float* hr = &hl[(tid >> 6) << 6];
#pragma unroll
    for (int k = 0; k < 64; ++k) acc += hr[k] * wl[k * 64 + j];
    float tj = fmaxf(acc, 0.f);
    float p0 = tj * W2[j * 4 + 0];
    float p1 = tj * W2[j * 4 + 1];
    float p2 = tj * W2[j * 4 + 2];
    float p3 = tj * W2[j * 4 + 3];
#pragma unroll
    for (int m = 32; m >= 1; m >>= 1) {
        p0 += __shfl_xor(p0, m, 64);
        p1 += __shfl_xor(p1, m, 64);
        p2 += __shfl_xor(p2, m, 64);
        p3 += __shfl_xor(p3, m, 64);
    }
    if (valid && j < 4) {
        float p = (j == 0) ? p0 : (j == 1) ? p1 : (j == 2) ? p2 : p3;
        out[v * 4 + j] = x[v * 4 + j] + p + b2[j];
    }
}

extern "C" void kernel_launch(void* const* d_in, const int* in_sizes, int n_in,
                              void* d_out, int out_size, void* d_ws, size_t ws_size,
                              hipStream_t stream) {
    const float* x     = (const float*)d_in[0];
    const int*   eidx  = (const int*)  d_in[1];
    const float* Win   = (const float*)d_in[2];
    const float* bin   = (const float*)d_in[3];
    const float* convw = (const float*)d_in[4];
    const float* convb = (const float*)d_in[5];
    const float* gamma = (const float*)d_in[6];
    const float* beta  = (const float*)d_in[7];
    const float* mean  = (const float*)d_in[8];
    const float* var   = (const float*)d_in[9];
    const float* W1    = (const float*)d_in[10];
    const float* b1    = (const float*)d_in[11];
    const float* W2    = (const float*)d_in[12];
    const float* b2    = (const float*)d_in[13];
    float* out = (float*)d_out;

    int n = in_sizes[0] / 4;   // 50000
    int E = in_sizes[1] / 2;   // 800000
    const int B = 256;
    int NB = (n + B - 1) / B;  // 196 blocks for the scan

    // workspace layout:
    // dinv[n] f32 | h[n*64] f32 | hws[n*64] bf16 | counts[n] | cursor[n] |
    // tmp[n] | rowptr[n+1] | bsum[256] | boff[256] | col[E]
    char* p = (char*)d_ws;
    size_t nh = (size_t)n * 64;
    float*          dinv   = (float*)p;          p += ((size_t)n + 16) * 4;
    float*          h      = (float*)p;          p += nh * 4;
    unsigned short* hws    = (unsigned short*)p; p += nh * 2;
    int*            counts = (int*)p;            p += (size_t)n * 4;
    int*            cursor = (int*)p;            p += (size_t)n * 4;
    int*            tmp    = (int*)p;            p += (size_t)n * 4;
    int*            rowptr = (int*)p;            p += ((size_t)n + 16) * 4;
    int*            bsum   = (int*)p;            p += 256 * 4;
    int*            boff   = (int*)p;            p += 256 * 4;
    int*            col    = (int*)p;            p += (size_t)E * 4;

    // ---- CSR build ----
    zero2<<<NB, B, 0, stream>>>(counts, cursor, n);
    hist_dst<<<(E + B - 1) / B, B, 0, stream>>>(eidx + E, counts, E);
    scan1<<<NB, B, 0, stream>>>(counts, tmp, bsum, dinv, n);
    scan2<<<1, B, 0, stream>>>(bsum, boff, NB);
    scan3b<<<NB, B, 0, stream>>>(counts, tmp, boff, rowptr, n, E);
    csr_fill<<<(E + B - 1) / B, B, 0, stream>>>(eidx, rowptr, cursor, col, E);

    // ---- network ----
    input_proj<<<(int)((nh + B - 1) / B), B, 0, stream>>>(x, Win, bin, h, n);
    int NB16 = (n + 15) / 16;
    for (int i = 0; i < 3; ++i) {
        gemm_hws<<<(n + 3) / 4, B, 0, stream>>>(h, convw + i * 4096, dinv, hws, n);
        gather_finalize<<<NB16, B, 0, stream>>>(
            rowptr, col, hws, dinv, h,
            convb + i * 64, gamma + i * 64, beta + i * 64, mean + i * 64, var + i * 64, n);
    }
    mlp_out<<<(n + 3) / 4, B, 0, stream>>>(h, x, W1, b1, W2, b2, out, n);
}